// Round 13
// baseline (309.285 us; speedup 1.0000x reference)
//
#include <hip/hip_runtime.h>
#include <cstdint>

#define K_DIM 4096
#define ROWB 13              // log2(K_DIM*2) byte row stride
#define NT   (K_DIM / 64)    // 64 K-tiles of 64 cols

typedef __bf16 bf16x8 __attribute__((ext_vector_type(8)));
typedef float f32x4  __attribute__((ext_vector_type(4)));
typedef float f32x16 __attribute__((ext_vector_type(16)));

// round-to-nearest-even float -> bf16 bits
__device__ inline unsigned short f2bf(float f) {
    union { float f; unsigned int u; } v; v.f = f;
    unsigned int u = v.u;
    return (unsigned short)((u + 0x7FFFu + ((u >> 16) & 1u)) >> 16);
}

__device__ __forceinline__ void gload16(const void* g, void* l) {
    __builtin_amdgcn_global_load_lds(
        (const __attribute__((address_space(1))) unsigned int*)g,
        (__attribute__((address_space(3))) unsigned int*)l,
        16, 0, 0);
}

// fused dequant of both operands: out[e] = bf16(q[e] * s[e/16])
__global__ __launch_bounds__(256) void dequant2_kernel(
        const float* __restrict__ qx, const float* __restrict__ sx,
        unsigned short* __restrict__ xd, long t8x,
        const float* __restrict__ qw, const float* __restrict__ sw,
        unsigned short* __restrict__ wd, long t8w) {
    long i = (long)blockIdx.x * blockDim.x + threadIdx.x;
    if (i >= t8x + t8w) return;
    const float* q; const float* s; unsigned short* o;
    if (i < t8x) { q = qx; s = sx; o = xd; }
    else         { q = qw; s = sw; o = wd; i -= t8x; }
    long e = i * 8;
    float sc = s[e >> 4];
    float4 v0 = *(const float4*)(q + e);
    float4 v1 = *(const float4*)(q + e + 4);
    union { unsigned short h[8]; uint4 u; } ov;
    ov.h[0] = f2bf(v0.x * sc); ov.h[1] = f2bf(v0.y * sc);
    ov.h[2] = f2bf(v0.z * sc); ov.h[3] = f2bf(v0.w * sc);
    ov.h[4] = f2bf(v1.x * sc); ov.h[5] = f2bf(v1.y * sc);
    ov.h[6] = f2bf(v1.z * sc); ov.h[7] = f2bf(v1.w * sc);
    *(uint4*)(o + e) = ov.u;
}

// ---- 256x256 bf16 GEMM — snake 4-phase + 32x32x16 MFMA ----
// r12's proven data path (staging, swizzle, vmcnt ladder, barriers) with
// only the MFMA shape changed: per-wave 128x64 out = 4x2 blocks of 32x32,
// 32 MFMA/wave/K-tile (vs 64 at 16x16), pipe ceiling 2495 vs 2075 TF.
// Under the 128B-row / chunk^=(row&7) swizzle the 32-row fragment read is
// conflict-free: lanes 0-7 (rows 0-7) XOR onto all 8 chunk slots = 32 banks.
// Phases per K-tile (snake, one operand reused per phase):
//   ph1: read A-lo(8)+B-lo(4) || stage A-lo(next) -> MFMA blk(0-1,0)
//   ph2: read B-hi(4)         || stage B-1(next)  -> MFMA blk(0-1,1)
//   ph3: read A-hi(8)         || stage B-2(next)  -> MFMA blk(2-3,1)
//   ph4: NO reads             || stage A-hi(next) -> MFMA blk(2-3,0)
// vmcnt(4) at ph2 close, vmcnt(2) at tile boundary (never drains to 0).

__global__ __launch_bounds__(512, 2) void gemm256_kernel(
        const unsigned short* __restrict__ A,   // [M][K] bf16
        const unsigned short* __restrict__ B,   // [N][K] bf16
        const float* __restrict__ sg1, const float* __restrict__ sg2,
        const float* __restrict__ bias,
        float* __restrict__ out, int M, int N) {
    __shared__ __align__(16) char lds[131072];   // 2 buffers x 64 KB

    const int tid  = threadIdx.x;
    const int lane = tid & 63;
    const int wid  = tid >> 6;       // 0..7
    const int wm   = wid >> 2;       // 0..1
    const int wn   = wid & 3;        // 0..3
    const int l31  = lane & 31;
    const int lhi  = lane >> 5;      // k-half
    const int rl7  = lane & 7;       // read-side row XOR (row&7 == lane&7)
    // per-kstep swizzled chunk offsets: chunk (2s+lhi) ^ rl7
    const int xs0 = ((0 + lhi) ^ rl7) << 4;
    const int xs1 = ((2 + lhi) ^ rl7) << 4;
    const int xs2 = ((4 + lhi) ^ rl7) << 4;
    const int xs3 = ((6 + lhi) ^ rl7) << 4;

    // XCD-aware bijective block swizzle (nwg % 8 == 0)
    const int nbn = N >> 8;
    const int nwg = (M >> 8) * nbn;
    const int cpx = nwg >> 3;
    const int bid = blockIdx.x;
    const int swz = (bid & 7) * cpx + (bid >> 3);
    const int tile_m = (swz / nbn) << 8;
    const int tile_n = (swz % nbn) << 8;

    // wave-private staging cursors (tile-0 addresses); +t*128 bytes per K-tile
    const int scb = ((lane & 7) ^ ((lane >> 3) & 7)) << 4;   // pre-swizzled chunk
    const char* gA1 = (const char*)A +
        ((size_t)(tile_m + wm * 128 + wn * 16 + (lane >> 3)) << ROWB) + scb;
    const char* gA2 = gA1 + ((size_t)64 << ROWB);
    const char* gBs = (const char*)B +
        ((size_t)(tile_n + wn * 64 + wm * 32 + (lane >> 3)) << ROWB) + scb;
    // LDS staging dests (wave-uniform bases), within a 64KB buffer
    const int dA1 = (wm * 128 + wn * 16) * 128;          // A at [0,32K)
    const int dA2 = dA1 + 8192;                          // +64 rows
    const int dB  = 32768 + (wn * 64 + wm * 32) * 128;   // B at [32K,64K)

    // fragment read bases (within buffer): +mb*4096 / +nb*4096, + xs_k
    const int aB = (wm * 128 + l31) * 128;
    const int bB = 32768 + (wn * 64 + l31) * 128;

    f32x16 acc[4][2];
#pragma unroll
    for (int mb = 0; mb < 4; ++mb)
#pragma unroll
        for (int nb = 0; nb < 2; ++nb)
#pragma unroll
            for (int j = 0; j < 16; ++j) acc[mb][nb][j] = 0.f;

    // prologue: stage tile 0 into buffer 0 (own slices, read order), drain
    gload16(gA1, lds + dA1);
    gload16(gA1 + ((size_t)8 << ROWB), lds + dA1 + 1024);
    gload16(gBs, lds + dB);
    gload16(gBs + ((size_t)8 << ROWB), lds + dB + 1024);
    gload16(gBs + ((size_t)16 << ROWB), lds + dB + 2048);
    gload16(gBs + ((size_t)24 << ROWB), lds + dB + 3072);
    gload16(gA2, lds + dA2);
    gload16(gA2 + ((size_t)8 << ROWB), lds + dA2 + 1024);
    asm volatile("s_waitcnt vmcnt(0)" ::: "memory");
    __builtin_amdgcn_s_barrier();

#define RD(P) *(const bf16x8*)(P)
#define TILE_BODY(T, CB, SB) do {                                            \
    const int ts_ = ((T) + 1 < NT) ? (T) + 1 : NT - 1;                       \
    const size_t tso = (size_t)ts_ * 128;                                    \
    bf16x8 af[2][4], af2[2][4], bf[4], bf2[4];                               \
    /* ---- ph1: read A-lo + B-lo || stage A-lo(next); MFMA blk(0-1,0) */    \
    _Pragma("unroll")                                                        \
    for (int mb = 0; mb < 2; ++mb) {                                         \
        af[mb][0] = RD(lds + (CB) + aB + mb * 4096 + xs0);                   \
        af[mb][1] = RD(lds + (CB) + aB + mb * 4096 + xs1);                   \
        af[mb][2] = RD(lds + (CB) + aB + mb * 4096 + xs2);                   \
        af[mb][3] = RD(lds + (CB) + aB + mb * 4096 + xs3);                   \
    }                                                                        \
    bf[0] = RD(lds + (CB) + bB + xs0);                                       \
    bf[1] = RD(lds + (CB) + bB + xs1);                                       \
    bf[2] = RD(lds + (CB) + bB + xs2);                                       \
    bf[3] = RD(lds + (CB) + bB + xs3);                                       \
    gload16(gA1 + tso, lds + (SB) + dA1);                                    \
    gload16(gA1 + tso + ((size_t)8 << ROWB), lds + (SB) + dA1 + 1024);       \
    __builtin_amdgcn_s_barrier();                                            \
    asm volatile("s_waitcnt lgkmcnt(0)" ::: "memory");                       \
    __builtin_amdgcn_s_setprio(1);                                           \
    _Pragma("unroll")                                                        \
    for (int s = 0; s < 4; ++s)                                              \
        _Pragma("unroll")                                                    \
        for (int mb = 0; mb < 2; ++mb)                                       \
            acc[mb][0] = __builtin_amdgcn_mfma_f32_32x32x16_bf16(            \
                af[mb][s], bf[s], acc[mb][0], 0, 0, 0);                      \
    __builtin_amdgcn_s_setprio(0);                                           \
    __builtin_amdgcn_s_barrier();                                            \
    /* ---- ph2: read B-hi || stage B-1(next); MFMA blk(0-1,1) */            \
    bf2[0] = RD(lds + (CB) + bB + 4096 + xs0);                               \
    bf2[1] = RD(lds + (CB) + bB + 4096 + xs1);                               \
    bf2[2] = RD(lds + (CB) + bB + 4096 + xs2);                               \
    bf2[3] = RD(lds + (CB) + bB + 4096 + xs3);                               \
    gload16(gBs + tso, lds + (SB) + dB);                                     \
    gload16(gBs + tso + ((size_t)8 << ROWB), lds + (SB) + dB + 1024);        \
    __builtin_amdgcn_s_barrier();                                            \
    asm volatile("s_waitcnt lgkmcnt(0)" ::: "memory");                       \
    __builtin_amdgcn_s_setprio(1);                                           \
    _Pragma("unroll")                                                        \
    for (int s = 0; s < 4; ++s)                                              \
        _Pragma("unroll")                                                    \
        for (int mb = 0; mb < 2; ++mb)                                       \
            acc[mb][1] = __builtin_amdgcn_mfma_f32_32x32x16_bf16(            \
                af[mb][s], bf2[s], acc[mb][1], 0, 0, 0);                     \
    __builtin_amdgcn_s_setprio(0);                                           \
    asm volatile("s_waitcnt vmcnt(4)" ::: "memory");                         \
    __builtin_amdgcn_s_barrier();                                            \
    /* ---- ph3: read A-hi || stage B-2(next); MFMA blk(2-3,1) */            \
    _Pragma("unroll")                                                        \
    for (int mb = 0; mb < 2; ++mb) {                                         \
        af2[mb][0] = RD(lds + (CB) + aB + 8192 + mb * 4096 + xs0);           \
        af2[mb][1] = RD(lds + (CB) + aB + 8192 + mb * 4096 + xs1);           \
        af2[mb][2] = RD(lds + (CB) + aB + 8192 + mb * 4096 + xs2);           \
        af2[mb][3] = RD(lds + (CB) + aB + 8192 + mb * 4096 + xs3);           \
    }                                                                        \
    gload16(gBs + tso + ((size_t)16 << ROWB), lds + (SB) + dB + 2048);       \
    gload16(gBs + tso + ((size_t)24 << ROWB), lds + (SB) + dB + 3072);       \
    __builtin_amdgcn_s_barrier();                                            \
    asm volatile("s_waitcnt lgkmcnt(0)" ::: "memory");                       \
    __builtin_amdgcn_s_setprio(1);                                           \
    _Pragma("unroll")                                                        \
    for (int s = 0; s < 4; ++s)                                              \
        _Pragma("unroll")                                                    \
        for (int mb = 0; mb < 2; ++mb)                                       \
            acc[2 + mb][1] = __builtin_amdgcn_mfma_f32_32x32x16_bf16(        \
                af2[mb][s], bf2[s], acc[2 + mb][1], 0, 0, 0);                \
    __builtin_amdgcn_s_setprio(0);                                           \
    __builtin_amdgcn_s_barrier();                                            \
    /* ---- ph4: NO reads || stage A-hi(next); MFMA blk(2-3,0) */            \
    gload16(gA2 + tso, lds + (SB) + dA2);                                    \
    gload16(gA2 + tso + ((size_t)8 << ROWB), lds + (SB) + dA2 + 1024);       \
    __builtin_amdgcn_s_setprio(1);                                           \
    _Pragma("unroll")                                                        \
    for (int s = 0; s < 4; ++s)                                              \
        _Pragma("unroll")                                                    \
        for (int mb = 0; mb < 2; ++mb)                                       \
            acc[2 + mb][0] = __builtin_amdgcn_mfma_f32_32x32x16_bf16(        \
                af2[mb][s], bf[s], acc[2 + mb][0], 0, 0, 0);                 \
    __builtin_amdgcn_s_setprio(0);                                           \
    asm volatile("s_waitcnt vmcnt(2)" ::: "memory");                         \
    __builtin_amdgcn_s_barrier();                                            \
} while (0)

    for (int t = 0; t < NT; t += 2) {
        TILE_BODY(t,     0,     65536);
        TILE_BODY(t + 1, 65536, 0);
    }
#undef TILE_BODY
#undef RD

    // epilogue: 32x32 C/D layout col=lane&31, row=(reg&3)+8*(reg>>2)+4*(lane>>5)
    const float gs = sg1[0] * sg2[0];
    const int row0 = tile_m + wm * 128 + 4 * lhi;
    const int col0 = tile_n + wn * 64 + l31;
    float bv[2];
#pragma unroll
    for (int nb = 0; nb < 2; ++nb) bv[nb] = bias[col0 + nb * 32];
#pragma unroll
    for (int mb = 0; mb < 4; ++mb)
#pragma unroll
        for (int nb = 0; nb < 2; ++nb) {
            const int col = col0 + nb * 32;
#pragma unroll
            for (int g = 0; g < 4; ++g)
#pragma unroll
                for (int r = 0; r < 4; ++r) {
                    const int row = row0 + mb * 32 + 8 * g + r;
                    out[(size_t)row * N + col] =
                        acc[mb][nb][g * 4 + r] * gs + bv[nb];
                }
        }
}

// ---------------- fallback: fused-dequant 128^2 GEMM (ws too small) ----------------
__global__ __launch_bounds__(256) void gemm_fused_kernel(
        const float* __restrict__ qx, const float* __restrict__ sx,
        const float* __restrict__ qw, const float* __restrict__ sw,
        const float* __restrict__ sg1, const float* __restrict__ sg2,
        const float* __restrict__ bias,
        float* __restrict__ out, int M, int N) {
    __shared__ __align__(16) unsigned short As[128 * 32];
    __shared__ __align__(16) unsigned short Bs[128 * 32];
    const int tid  = threadIdx.x;
    const int lane = tid & 63;
    const int wid  = tid >> 6;
    const int tile_n = blockIdx.x * 128;
    const int tile_m = blockIdx.y * 128;
    const int wm = wid >> 1, wn = wid & 1;
    f32x4 acc[16];
#pragma unroll
    for (int i = 0; i < 16; ++i) acc[i] = (f32x4){0.f, 0.f, 0.f, 0.f};
    const int l15 = lane & 15;
    const int lk  = (lane >> 4) * 8;
    for (int kt = 0; kt < K_DIM / 32; ++kt) {
#pragma unroll
        for (int cc = 0; cc < 2; ++cc) {
            const int c   = tid + cc * 256;
            const int row = c >> 2;
            const int col = (c & 3) * 8;
            const int gk  = kt * 32 + col;
            {
                const float* qp = qx + (long)(tile_m + row) * K_DIM + gk;
                float s = sx[(long)(tile_m + row) * (K_DIM / 16) + (gk >> 4)];
                float4 a0 = *(const float4*)qp;
                float4 a1 = *(const float4*)(qp + 4);
                union { unsigned short h[8]; uint4 u; } o;
                o.h[0] = f2bf(a0.x * s); o.h[1] = f2bf(a0.y * s);
                o.h[2] = f2bf(a0.z * s); o.h[3] = f2bf(a0.w * s);
                o.h[4] = f2bf(a1.x * s); o.h[5] = f2bf(a1.y * s);
                o.h[6] = f2bf(a1.z * s); o.h[7] = f2bf(a1.w * s);
                *(uint4*)&As[row * 32 + col] = o.u;
            }
            {
                const float* qp = qw + (long)(tile_n + row) * K_DIM + gk;
                float s = sw[(long)(tile_n + row) * (K_DIM / 16) + (gk >> 4)];
                float4 a0 = *(const float4*)qp;
                float4 a1 = *(const float4*)(qp + 4);
                union { unsigned short h[8]; uint4 u; } o;
                o.h[0] = f2bf(a0.x * s); o.h[1] = f2bf(a0.y * s);
                o.h[2] = f2bf(a0.z * s); o.h[3] = f2bf(a0.w * s);
                o.h[4] = f2bf(a1.x * s); o.h[5] = f2bf(a1.y * s);
                o.h[6] = f2bf(a1.z * s); o.h[7] = f2bf(a1.w * s);
                *(uint4*)&Bs[row * 32 + col] = o.u;
            }
        }
        __syncthreads();
        const unsigned short* pa = As + (wm * 64 + l15) * 32 + lk;
        const unsigned short* pb = Bs + (wn * 64 + l15) * 32 + lk;
        bf16x8 a[4], b[4];
#pragma unroll
        for (int i = 0; i < 4; ++i) {
            a[i] = *(const bf16x8*)(pa + i * 16 * 32);
            b[i] = *(const bf16x8*)(pb + i * 16 * 32);
        }
#pragma unroll
        for (int mi = 0; mi < 4; ++mi)
#pragma unroll
            for (int ni = 0; ni < 4; ++ni)
                acc[mi * 4 + ni] = __builtin_amdgcn_mfma_f32_16x16x32_bf16(
                    a[mi], b[ni], acc[mi * 4 + ni], 0, 0, 0);
        __syncthreads();
    }
    const float gs = sg1[0] * sg2[0];
    const int row0 = tile_m + wm * 64 + (lane >> 4) * 4;
    const int col0 = tile_n + wn * 64 + l15;
#pragma unroll
    for (int mi = 0; mi < 4; ++mi)
#pragma unroll
        for (int ni = 0; ni < 4; ++ni) {
            const int col = col0 + ni * 16;
            const float bv = bias[col];
#pragma unroll
            for (int j = 0; j < 4; ++j)
                out[(long)(row0 + mi * 16 + j) * N + col] =
                    acc[mi * 4 + ni][j] * gs + bv;
        }
}

extern "C" void kernel_launch(void* const* d_in, const int* in_sizes, int n_in,
                              void* d_out, int out_size, void* d_ws, size_t ws_size,
                              hipStream_t stream) {
    const float* qx   = (const float*)d_in[0];
    const float* sx   = (const float*)d_in[1];
    const float* sc   = (const float*)d_in[2];
    const float* qw   = (const float*)d_in[3];
    const float* sw   = (const float*)d_in[4];
    const float* swg  = (const float*)d_in[5];
    const float* bias = (const float*)d_in[6];
    float* out = (float*)d_out;

    const int M = in_sizes[0] / K_DIM;   // 8192
    const int N = in_sizes[3] / K_DIM;   // 4096

    const size_t needA = (size_t)M * K_DIM * sizeof(unsigned short);
    const size_t needB = (size_t)N * K_DIM * sizeof(unsigned short);

    if (ws_size >= needA + needB) {
        unsigned short* xd = (unsigned short*)d_ws;
        unsigned short* wd = (unsigned short*)((char*)d_ws + needA);
        long t8x = (long)M * K_DIM / 8;
        long t8w = (long)N * K_DIM / 8;
        long tot = t8x + t8w;
        dequant2_kernel<<<(int)((tot + 255) / 256), 256, 0, stream>>>(
            qx, sx, xd, t8x, qw, sw, wd, t8w);
        const int nwg = (M / 256) * (N / 256);
        gemm256_kernel<<<nwg, 512, 0, stream>>>(xd, wd, sc, swg, bias, out, M, N);
    } else {
        dim3 grid(N / 128, M / 128);
        gemm_fused_kernel<<<grid, 256, 0, stream>>>(
            qx, sx, qw, sw, sc, swg, bias, out, M, N);
    }
}

// Round 14
// 270.728 us; speedup vs baseline: 1.1424x; 1.1424x over previous
//
#include <hip/hip_runtime.h>
#include <cstdint>

#define K_DIM 4096
#define ROWB 13              // log2(K_DIM*2) byte row stride
#define NT   (K_DIM / 64)    // 64 K-tiles of 64 cols

typedef __bf16 bf16x8 __attribute__((ext_vector_type(8)));
typedef float f32x4 __attribute__((ext_vector_type(4)));

// round-to-nearest-even float -> bf16 bits
__device__ inline unsigned short f2bf(float f) {
    union { float f; unsigned int u; } v; v.f = f;
    unsigned int u = v.u;
    return (unsigned short)((u + 0x7FFFu + ((u >> 16) & 1u)) >> 16);
}

__device__ __forceinline__ void gload16(const void* g, void* l) {
    __builtin_amdgcn_global_load_lds(
        (const __attribute__((address_space(1))) unsigned int*)g,
        (__attribute__((address_space(3))) unsigned int*)l,
        16, 0, 0);
}

// fused dequant of both operands: out[e] = bf16(q[e] * s[e/16])
__global__ __launch_bounds__(256) void dequant2_kernel(
        const float* __restrict__ qx, const float* __restrict__ sx,
        unsigned short* __restrict__ xd, long t8x,
        const float* __restrict__ qw, const float* __restrict__ sw,
        unsigned short* __restrict__ wd, long t8w) {
    long i = (long)blockIdx.x * blockDim.x + threadIdx.x;
    if (i >= t8x + t8w) return;
    const float* q; const float* s; unsigned short* o;
    if (i < t8x) { q = qx; s = sx; o = xd; }
    else         { q = qw; s = sw; o = wd; i -= t8x; }
    long e = i * 8;
    float sc = s[e >> 4];
    float4 v0 = *(const float4*)(q + e);
    float4 v1 = *(const float4*)(q + e + 4);
    union { unsigned short h[8]; uint4 u; } ov;
    ov.h[0] = f2bf(v0.x * sc); ov.h[1] = f2bf(v0.y * sc);
    ov.h[2] = f2bf(v0.z * sc); ov.h[3] = f2bf(v0.w * sc);
    ov.h[4] = f2bf(v1.x * sc); ov.h[5] = f2bf(v1.y * sc);
    ov.h[6] = f2bf(v1.z * sc); ov.h[7] = f2bf(v1.w * sc);
    *(uint4*)(o + e) = ov.u;
}

// ---- 256x256 bf16 GEMM — snake 4-phase, balanced reads 8/4/8/4 ----
// r12's data path (swizzle, 16x16x32 MFMA, 0 conflicts) with B-lo(t+1)
// read in ph4(t) from the next buffer and staging reordered B1,B2,Alo,Ahi.
// Phases per K-tile t (buffer CB; staging t+1 into SB):
//   ph1: read A-lo(8)       || stage B1(next) -> MFMA Q00 (B-lo from ph4 regs)
//   ph2: read B-hi(4)       || stage B2(next) -> MFMA Q01 (A-lo live)
//        vmcnt(4): publishes A-hi(t)
//   ph3: read A-hi(8)       || stage Alo(next)-> MFMA Q11 (B-hi live)
//        vmcnt(2): publishes B-lo(t+1)
//   ph4: read B-lo(next)(4) || stage Ahi(next)-> MFMA Q10 (A-hi, B-lo live)
//        vmcnt(2): publishes A-lo(t+1)
// Counted vmcnt never drains to 0. Swizzle: chunk c of 128B row r stored
// at c ^ (r&7); inverse pre-applied to per-lane GLOBAL source address.

__global__ __launch_bounds__(512, 2) void gemm256_kernel(
        const unsigned short* __restrict__ A,   // [M][K] bf16
        const unsigned short* __restrict__ B,   // [N][K] bf16
        const float* __restrict__ sg1, const float* __restrict__ sg2,
        const float* __restrict__ bias,
        float* __restrict__ out, int M, int N) {
    __shared__ __align__(16) char lds[131072];   // 2 buffers x 64 KB

    const int tid  = threadIdx.x;
    const int lane = tid & 63;
    const int wid  = tid >> 6;       // 0..7
    const int wm   = wid >> 2;       // 0..1
    const int wn   = wid & 3;        // 0..3
    const int l15  = lane & 15;
    const int cb4  = lane >> 4;      // 0..3: 16B chunk within 32-col ksub
    const int rx   = l15 & 7;        // read-side row XOR
    const int xk0  = (cb4 ^ rx) << 4;
    const int xk1  = ((4 + cb4) ^ rx) << 4;

    // XCD-aware bijective block swizzle (nwg % 8 == 0)
    const int nbn = N >> 8;
    const int nwg = (M >> 8) * nbn;
    const int cpx = nwg >> 3;
    const int bid = blockIdx.x;
    const int swz = (bid & 7) * cpx + (bid >> 3);
    const int tile_m = (swz / nbn) << 8;
    const int tile_n = (swz % nbn) << 8;

    // wave-private staging cursors (tile-0 addresses); +t*128 bytes per K-tile
    const int scb = ((lane & 7) ^ ((lane >> 3) & 7)) << 4;   // pre-swizzled chunk
    const char* gA1 = (const char*)A +
        ((size_t)(tile_m + wm * 128 + wn * 16 + (lane >> 3)) << ROWB) + scb;
    const char* gA2 = gA1 + ((size_t)64 << ROWB);
    const char* gBs = (const char*)B +
        ((size_t)(tile_n + wn * 64 + wm * 32 + (lane >> 3)) << ROWB) + scb;
    // LDS staging dests (wave-uniform bases), within a 64KB buffer
    const int dA1 = (wm * 128 + wn * 16) * 128;          // A at [0,32K)
    const int dA2 = dA1 + 8192;                          // +64 rows
    const int dB  = 32768 + (wn * 64 + wm * 32) * 128;   // B at [32K,64K)

    // fragment read bases (within buffer): +mb*2048 +xk
    const int aB = (wm * 128 + l15) * 128;
    const int bB = 32768 + (wn * 64 + l15) * 128;

    f32x4 acc[8][4];
#pragma unroll
    for (int mb = 0; mb < 8; ++mb)
#pragma unroll
        for (int nb = 0; nb < 4; ++nb) acc[mb][nb] = (f32x4){0.f, 0.f, 0.f, 0.f};

    bf16x8 bfA[4], bfB[4];   // B-lo double buffer (cur/next)

    // prologue: stage tile 0 into buffer 0, drain, read B-lo(0) -> bfA
    gload16(gBs, lds + dB);
    gload16(gBs + ((size_t)8 << ROWB), lds + dB + 1024);
    gload16(gBs + ((size_t)16 << ROWB), lds + dB + 2048);
    gload16(gBs + ((size_t)24 << ROWB), lds + dB + 3072);
    gload16(gA1, lds + dA1);
    gload16(gA1 + ((size_t)8 << ROWB), lds + dA1 + 1024);
    gload16(gA2, lds + dA2);
    gload16(gA2 + ((size_t)8 << ROWB), lds + dA2 + 1024);
    asm volatile("s_waitcnt vmcnt(0)" ::: "memory");
    __builtin_amdgcn_s_barrier();
#pragma unroll
    for (int nb = 0; nb < 2; ++nb) {
        bfA[nb * 2 + 0] = *(const bf16x8*)(lds + bB + nb * 2048 + xk0);
        bfA[nb * 2 + 1] = *(const bf16x8*)(lds + bB + nb * 2048 + xk1);
    }

#define TILE_BODY(T, CB, SB, BFC, BFN) do {                                  \
    const int ts_ = ((T) + 1 < NT) ? (T) + 1 : NT - 1;                       \
    const size_t tso = (size_t)ts_ * 128;                                    \
    bf16x8 af[8], af2[8], bf2[4];                                            \
    /* ---- ph1: read A-lo(8) || stage B1(next); MFMA Q00 (BFC) ---- */      \
    _Pragma("unroll")                                                        \
    for (int mb = 0; mb < 4; ++mb) {                                         \
        af[mb * 2 + 0] = *(const bf16x8*)(lds + (CB) + aB + mb * 2048 + xk0);\
        af[mb * 2 + 1] = *(const bf16x8*)(lds + (CB) + aB + mb * 2048 + xk1);\
    }                                                                        \
    gload16(gBs + tso, lds + (SB) + dB);                                     \
    gload16(gBs + tso + ((size_t)8 << ROWB), lds + (SB) + dB + 1024);        \
    __builtin_amdgcn_s_barrier();                                            \
    asm volatile("s_waitcnt lgkmcnt(0)" ::: "memory");                       \
    __builtin_amdgcn_s_setprio(1);                                           \
    _Pragma("unroll")                                                        \
    for (int mb = 0; mb < 4; ++mb)                                           \
        _Pragma("unroll")                                                    \
        for (int nb = 0; nb < 2; ++nb)                                       \
            _Pragma("unroll")                                                \
            for (int ks = 0; ks < 2; ++ks)                                   \
                acc[mb][nb] = __builtin_amdgcn_mfma_f32_16x16x32_bf16(       \
                    af[mb * 2 + ks], BFC[nb * 2 + ks], acc[mb][nb], 0, 0, 0);\
    __builtin_amdgcn_s_setprio(0);                                           \
    __builtin_amdgcn_s_barrier();                                            \
    /* ---- ph2: read B-hi(4) || stage B2(next); MFMA Q01 (A-lo live) */     \
    _Pragma("unroll")                                                        \
    for (int nb = 0; nb < 2; ++nb) {                                         \
        bf2[nb * 2 + 0] =                                                    \
            *(const bf16x8*)(lds + (CB) + bB + 4096 + nb * 2048 + xk0);      \
        bf2[nb * 2 + 1] =                                                    \
            *(const bf16x8*)(lds + (CB) + bB + 4096 + nb * 2048 + xk1);      \
    }                                                                        \
    gload16(gBs + tso + ((size_t)16 << ROWB), lds + (SB) + dB + 2048);       \
    gload16(gBs + tso + ((size_t)24 << ROWB), lds + (SB) + dB + 3072);       \
    __builtin_amdgcn_s_barrier();                                            \
    asm volatile("s_waitcnt lgkmcnt(0)" ::: "memory");                       \
    __builtin_amdgcn_s_setprio(1);                                           \
    _Pragma("unroll")                                                        \
    for (int mb = 0; mb < 4; ++mb)                                           \
        _Pragma("unroll")                                                    \
        for (int nb = 0; nb < 2; ++nb)                                       \
            _Pragma("unroll")                                                \
            for (int ks = 0; ks < 2; ++ks)                                   \
                acc[mb][2 + nb] = __builtin_amdgcn_mfma_f32_16x16x32_bf16(   \
                    af[mb * 2 + ks], bf2[nb * 2 + ks], acc[mb][2 + nb],      \
                    0, 0, 0);                                                \
    __builtin_amdgcn_s_setprio(0);                                           \
    asm volatile("s_waitcnt vmcnt(4)" ::: "memory");   /* A-hi(t) landed */  \
    __builtin_amdgcn_s_barrier();                                            \
    /* ---- ph3: read A-hi(8) || stage Alo(next); MFMA Q11 (B-hi live) */    \
    _Pragma("unroll")                                                        \
    for (int mb = 0; mb < 4; ++mb) {                                         \
        af2[mb * 2 + 0] =                                                    \
            *(const bf16x8*)(lds + (CB) + aB + 8192 + mb * 2048 + xk0);      \
        af2[mb * 2 + 1] =                                                    \
            *(const bf16x8*)(lds + (CB) + aB + 8192 + mb * 2048 + xk1);      \
    }                                                                        \
    gload16(gA1 + tso, lds + (SB) + dA1);                                    \
    gload16(gA1 + tso + ((size_t)8 << ROWB), lds + (SB) + dA1 + 1024);       \
    __builtin_amdgcn_s_barrier();                                            \
    asm volatile("s_waitcnt lgkmcnt(0)" ::: "memory");                       \
    __builtin_amdgcn_s_setprio(1);                                           \
    _Pragma("unroll")                                                        \
    for (int mb = 0; mb < 4; ++mb)                                           \
        _Pragma("unroll")                                                    \
        for (int nb = 0; nb < 2; ++nb)                                       \
            _Pragma("unroll")                                                \
            for (int ks = 0; ks < 2; ++ks)                                   \
                acc[4 + mb][2 + nb] = __builtin_amdgcn_mfma_f32_16x16x32_bf16(\
                    af2[mb * 2 + ks], bf2[nb * 2 + ks], acc[4 + mb][2 + nb], \
                    0, 0, 0);                                                \
    __builtin_amdgcn_s_setprio(0);                                           \
    asm volatile("s_waitcnt vmcnt(2)" ::: "memory");   /* B-lo(t+1) landed */\
    __builtin_amdgcn_s_barrier();                                            \
    /* ---- ph4: read B-lo(next)(4) from SB || stage Ahi(next); MFMA Q10 */  \
    _Pragma("unroll")                                                        \
    for (int nb = 0; nb < 2; ++nb) {                                         \
        BFN[nb * 2 + 0] = *(const bf16x8*)(lds + (SB) + bB + nb * 2048 + xk0);\
        BFN[nb * 2 + 1] = *(const bf16x8*)(lds + (SB) + bB + nb * 2048 + xk1);\
    }                                                                        \
    gload16(gA2 + tso, lds + (SB) + dA2);                                    \
    gload16(gA2 + tso + ((size_t)8 << ROWB), lds + (SB) + dA2 + 1024);       \
    __builtin_amdgcn_s_setprio(1);                                           \
    _Pragma("unroll")                                                        \
    for (int mb = 0; mb < 4; ++mb)                                           \
        _Pragma("unroll")                                                    \
        for (int nb = 0; nb < 2; ++nb)                                       \
            _Pragma("unroll")                                                \
            for (int ks = 0; ks < 2; ++ks)                                   \
                acc[4 + mb][nb] = __builtin_amdgcn_mfma_f32_16x16x32_bf16(   \
                    af2[mb * 2 + ks], BFC[nb * 2 + ks], acc[4 + mb][nb],     \
                    0, 0, 0);                                                \
    __builtin_amdgcn_s_setprio(0);                                           \
    asm volatile("s_waitcnt vmcnt(2)" ::: "memory");   /* A-lo(t+1) landed */\
    __builtin_amdgcn_s_barrier();                                            \
} while (0)

    for (int t = 0; t < NT; t += 2) {
        TILE_BODY(t,     0,     65536, bfA, bfB);
        TILE_BODY(t + 1, 65536, 0,     bfB, bfA);
    }
#undef TILE_BODY

    // epilogue: C/D layout col=lane&15, row=(lane>>4)*4+j
    const float gs = sg1[0] * sg2[0];
    const int row0 = tile_m + wm * 128 + (cb4 << 2);
    const int col0 = tile_n + wn * 64 + l15;
    float bv[4];
#pragma unroll
    for (int nb = 0; nb < 4; ++nb) bv[nb] = bias[col0 + nb * 16];
#pragma unroll
    for (int mb = 0; mb < 8; ++mb)
#pragma unroll
        for (int nb = 0; nb < 4; ++nb) {
            const int col = col0 + nb * 16;
#pragma unroll
            for (int j = 0; j < 4; ++j)
                out[(size_t)(row0 + mb * 16 + j) * N + col] =
                    acc[mb][nb][j] * gs + bv[nb];
        }
}

// ---------------- fallback: fused-dequant 128^2 GEMM (ws too small) ----------------
__global__ __launch_bounds__(256) void gemm_fused_kernel(
        const float* __restrict__ qx, const float* __restrict__ sx,
        const float* __restrict__ qw, const float* __restrict__ sw,
        const float* __restrict__ sg1, const float* __restrict__ sg2,
        const float* __restrict__ bias,
        float* __restrict__ out, int M, int N) {
    __shared__ __align__(16) unsigned short As[128 * 32];
    __shared__ __align__(16) unsigned short Bs[128 * 32];
    const int tid  = threadIdx.x;
    const int lane = tid & 63;
    const int wid  = tid >> 6;
    const int tile_n = blockIdx.x * 128;
    const int tile_m = blockIdx.y * 128;
    const int wm = wid >> 1, wn = wid & 1;
    f32x4 acc[16];
#pragma unroll
    for (int i = 0; i < 16; ++i) acc[i] = (f32x4){0.f, 0.f, 0.f, 0.f};
    const int l15 = lane & 15;
    const int lk  = (lane >> 4) * 8;
    for (int kt = 0; kt < K_DIM / 32; ++kt) {
#pragma unroll
        for (int cc = 0; cc < 2; ++cc) {
            const int c   = tid + cc * 256;
            const int row = c >> 2;
            const int col = (c & 3) * 8;
            const int gk  = kt * 32 + col;
            {
                const float* qp = qx + (long)(tile_m + row) * K_DIM + gk;
                float s = sx[(long)(tile_m + row) * (K_DIM / 16) + (gk >> 4)];
                float4 a0 = *(const float4*)qp;
                float4 a1 = *(const float4*)(qp + 4);
                union { unsigned short h[8]; uint4 u; } o;
                o.h[0] = f2bf(a0.x * s); o.h[1] = f2bf(a0.y * s);
                o.h[2] = f2bf(a0.z * s); o.h[3] = f2bf(a0.w * s);
                o.h[4] = f2bf(a1.x * s); o.h[5] = f2bf(a1.y * s);
                o.h[6] = f2bf(a1.z * s); o.h[7] = f2bf(a1.w * s);
                *(uint4*)&As[row * 32 + col] = o.u;
            }
            {
                const float* qp = qw + (long)(tile_n + row) * K_DIM + gk;
                float s = sw[(long)(tile_n + row) * (K_DIM / 16) + (gk >> 4)];
                float4 a0 = *(const float4*)qp;
                float4 a1 = *(const float4*)(qp + 4);
                union { unsigned short h[8]; uint4 u; } o;
                o.h[0] = f2bf(a0.x * s); o.h[1] = f2bf(a0.y * s);
                o.h[2] = f2bf(a0.z * s); o.h[3] = f2bf(a0.w * s);
                o.h[4] = f2bf(a1.x * s); o.h[5] = f2bf(a1.y * s);
                o.h[6] = f2bf(a1.z * s); o.h[7] = f2bf(a1.w * s);
                *(uint4*)&Bs[row * 32 + col] = o.u;
            }
        }
        __syncthreads();
        const unsigned short* pa = As + (wm * 64 + l15) * 32 + lk;
        const unsigned short* pb = Bs + (wn * 64 + l15) * 32 + lk;
        bf16x8 a[4], b[4];
#pragma unroll
        for (int i = 0; i < 4; ++i) {
            a[i] = *(const bf16x8*)(pa + i * 16 * 32);
            b[i] = *(const bf16x8*)(pb + i * 16 * 32);
        }
#pragma unroll
        for (int mi = 0; mi < 4; ++mi)
#pragma unroll
            for (int ni = 0; ni < 4; ++ni)
                acc[mi * 4 + ni] = __builtin_amdgcn_mfma_f32_16x16x32_bf16(
                    a[mi], b[ni], acc[mi * 4 + ni], 0, 0, 0);
        __syncthreads();
    }
    const float gs = sg1[0] * sg2[0];
    const int row0 = tile_m + wm * 64 + (lane >> 4) * 4;
    const int col0 = tile_n + wn * 64 + l15;
#pragma unroll
    for (int mi = 0; mi < 4; ++mi)
#pragma unroll
        for (int ni = 0; ni < 4; ++ni) {
            const int col = col0 + ni * 16;
            const float bv = bias[col];
#pragma unroll
            for (int j = 0; j < 4; ++j)
                out[(long)(row0 + mi * 16 + j) * N + col] =
                    acc[mi * 4 + ni][j] * gs + bv;
        }
}

extern "C" void kernel_launch(void* const* d_in, const int* in_sizes, int n_in,
                              void* d_out, int out_size, void* d_ws, size_t ws_size,
                              hipStream_t stream) {
    const float* qx   = (const float*)d_in[0];
    const float* sx   = (const float*)d_in[1];
    const float* sc   = (const float*)d_in[2];
    const float* qw   = (const float*)d_in[3];
    const float* sw   = (const float*)d_in[4];
    const float* swg  = (const float*)d_in[5];
    const float* bias = (const float*)d_in[6];
    float* out = (float*)d_out;

    const int M = in_sizes[0] / K_DIM;   // 8192
    const int N = in_sizes[3] / K_DIM;   // 4096

    const size_t needA = (size_t)M * K_DIM * sizeof(unsigned short);
    const size_t needB = (size_t)N * K_DIM * sizeof(unsigned short);

    if (ws_size >= needA + needB) {
        unsigned short* xd = (unsigned short*)d_ws;
        unsigned short* wd = (unsigned short*)((char*)d_ws + needA);
        long t8x = (long)M * K_DIM / 8;
        long t8w = (long)N * K_DIM / 8;
        long tot = t8x + t8w;
        dequant2_kernel<<<(int)((tot + 255) / 256), 256, 0, stream>>>(
            qx, sx, xd, t8x, qw, sw, wd, t8w);
        const int nwg = (M / 256) * (N / 256);
        gemm256_kernel<<<nwg, 512, 0, stream>>>(xd, wd, sc, swg, bias, out, M, N);
    } else {
        dim3 grid(N / 128, M / 128);
        gemm_fused_kernel<<<grid, 256, 0, stream>>>(
            qx, sx, qw, sw, sc, swg, bias, out, M, N);
    }
}